// Round 6
// baseline (447.389 us; speedup 1.0000x reference)
//
#include <hip/hip_runtime.h>

// MHA-no-softmax, re-associated:  out = rope(XWq+bq) · [ (rope(XWk+bk))^T (XWv+bv) ] / 4
// Round 6: fuse Q/K/V projections (one pass over X, Wall=[Wq;Wk;Wv]) and add
// bijective XCD swizzle + panel-chunked logical ordering to all GEMMs so blocks
// sharing an A row-panel land on the SAME XCD's L2 (round 5 measured 4.5x
// A-over-fetch from x-major dispatch spreading panel-sharers across 8 XCDs).
// GEMM core unchanged from validated round 5: 128x128 tile, BK=64, 4 waves,
// mfma_f32_16x16x32_f16, global_load_lds w=16, XOR-swizzled LDS (rule #21).
//
// Flow: cast x,wq,wk,wv -> f16 (Wall contiguous)
//   fused_proj -> qh[m][d] (ws), Kt[b][d][s] (d_out lo), Vt[b][d][s] (d_out hi)
//   ktv (split-K=2) -> part (ws, aliases dead xh) ; reduce -> Mt f16
//   qm -> out (fp32, overwrites Kt/Vt after ktv done)

typedef _Float16 f16;
typedef _Float16 f16x8 __attribute__((ext_vector_type(8)));
typedef _Float16 f16x4 __attribute__((ext_vector_type(4)));
typedef float f32x4 __attribute__((ext_vector_type(4)));

namespace {
constexpr int kB = 4, kS = 4096, kD = 1024;
constexpr int kBS = kB * kS;  // 16384
constexpr int TM = 128, TN = 128, BK = 64;
}  // namespace

__device__ __forceinline__ void gld_lds16(const f16* g, f16* l) {
  __builtin_amdgcn_global_load_lds(
      (const __attribute__((address_space(1))) unsigned int*)g,
      (__attribute__((address_space(3))) unsigned int*)l, 16, 0, 0);
}

__global__ void cast_f2h(const float* __restrict__ src, f16* __restrict__ dst,
                         int n) {
  const int stride = gridDim.x * blockDim.x * 8;
  for (int i = (blockIdx.x * blockDim.x + threadIdx.x) * 8; i < n; i += stride) {
    float4 a = *reinterpret_cast<const float4*>(src + i);
    float4 b = *reinterpret_cast<const float4*>(src + i + 4);
    f16x8 o = {(f16)a.x, (f16)a.y, (f16)a.z, (f16)a.w,
               (f16)b.x, (f16)b.y, (f16)b.z, (f16)b.w};
    *reinterpret_cast<f16x8*>(dst + i) = o;
  }
}

// partials p[(b*2+split)][1M] fp32 -> Mt[b][1M] f16
__global__ void reduce_mt(const float* __restrict__ p, f16* __restrict__ mt) {
  const int i = (blockIdx.x * blockDim.x + threadIdx.x) * 8;  // < 4M
  const int b = i >> 20;
  const int w = i & ((1 << 20) - 1);
  const float* p0 = p + ((size_t)(2 * b) << 20) + w;
  const float* p1 = p0 + (1 << 20);
  float4 a0 = *reinterpret_cast<const float4*>(p0);
  float4 a1 = *reinterpret_cast<const float4*>(p0 + 4);
  float4 c0 = *reinterpret_cast<const float4*>(p1);
  float4 c1 = *reinterpret_cast<const float4*>(p1 + 4);
  f16x8 o = {(f16)(a0.x + c0.x), (f16)(a0.y + c0.y), (f16)(a0.z + c0.z),
             (f16)(a0.w + c0.w), (f16)(a1.x + c1.x), (f16)(a1.y + c1.y),
             (f16)(a1.z + c1.z), (f16)(a1.w + c1.w)};
  *reinterpret_cast<f16x8*>(mt + i) = o;
}

// ---- shared 128x128 / BK=64 MFMA core (validated round 5) ----
template <int LDA, int LDB, int KSTEPS>
__device__ __forceinline__ void gemm_core(const f16* __restrict__ Ab,
                                          const f16* __restrict__ Bb, f16* sA,
                                          f16* sB, f32x4 (&acc)[4][4]) {
  const int tid = threadIdx.x;
  const int w = tid >> 6, lane = tid & 63;
  const int wm = w >> 1, wn = w & 1;
  const int srow = lane >> 3;         // row within 8-row chunk
  const int scolb = (lane & 7) * 16;  // col bytes within 128B row

#pragma unroll
  for (int i = 0; i < 4; ++i)
#pragma unroll
    for (int j = 0; j < 4; ++j) acc[i][j] = (f32x4){0.f, 0.f, 0.f, 0.f};

  for (int ks = 0; ks < KSTEPS; ++ks) {
    const int k0 = ks * BK;
    // linear LDS dest, inverse-swizzled global source (involution per rule #21)
#pragma unroll
    for (int i = 0; i < 4; ++i) {
      const int row = w * 32 + i * 8 + srow;
      const int fe = (scolb ^ ((row & 7) << 4)) >> 1;
      gld_lds16(Ab + (size_t)row * LDA + k0 + fe, sA + w * 2048 + i * 512);
      gld_lds16(Bb + (size_t)row * LDB + k0 + fe, sB + w * 2048 + i * 512);
    }
    __syncthreads();
#pragma unroll
    for (int kc = 0; kc < 2; ++kc) {
      const int clog = kc * 64 + (lane >> 4) * 16;  // logical col bytes
      f16x8 af[4], bf[4];
#pragma unroll
      for (int f = 0; f < 4; ++f) {
        const int ra = wm * 64 + f * 16 + (lane & 15);
        af[f] = *reinterpret_cast<const f16x8*>(
            sA + ra * BK + ((clog ^ ((ra & 7) << 4)) >> 1));
        const int rb = wn * 64 + f * 16 + (lane & 15);
        bf[f] = *reinterpret_cast<const f16x8*>(
            sB + rb * BK + ((clog ^ ((rb & 7) << 4)) >> 1));
      }
#pragma unroll
      for (int i = 0; i < 4; ++i)
#pragma unroll
        for (int j = 0; j < 4; ++j)
          acc[i][j] = __builtin_amdgcn_mfma_f32_16x16x32_f16(af[i], bf[j],
                                                             acc[i][j], 0, 0, 0);
    }
    __syncthreads();
  }
}

// ---- fused Q/K/V projection: grid 3072 (1-D, swizzled) ----
// logical l: rpc=l/384 (==XCD), r=l%384, ct=r/16 (0..23), rp=rpc*16+(r%15+1?no:r&15)
__global__ __launch_bounds__(256) void fused_proj(
    const f16* __restrict__ X, const f16* __restrict__ Wall,
    const float* __restrict__ bq, const float* __restrict__ bk,
    const float* __restrict__ bv, const float* __restrict__ fcos,
    const float* __restrict__ fsin, f16* __restrict__ qh, f16* __restrict__ Kt,
    f16* __restrict__ Vt) {
  __shared__ __align__(16) unsigned char smem_raw[34816];
  f16* sA = (f16*)smem_raw;
  f16* sB = sA + TM * BK;

  const int bid = blockIdx.x;
  const int l = (bid & 7) * 384 + (bid >> 3);  // bijective XCD swizzle
  const int rpc = l / 384;                     // XCD chunk: 16 row-panels (4MB)
  const int r = l % 384;
  const int ct = r >> 4;                 // 0..23 column tile (B streamed)
  const int rp = rpc * 16 + (r & 15);    // 0..127 row panel (A resident)
  const int m0 = rp * 128;
  const int n0 = ct * 128;               // row in Wall
  const int which = ct >> 3;             // 0=Q 1=K 2=V
  const int feat0 = (ct & 7) * 128;      // feature-dim base within projection

  f32x4 acc[4][4];
  gemm_core<kD, kD, kD / BK>(X + (size_t)m0 * kD, Wall + (size_t)n0 * kD, sA, sB,
                             acc);

  const int tid = threadIdx.x;
  const int w = tid >> 6, lane = tid & 63;
  const int wm = w >> 1, wn = w & 1;
  const int rbase = m0 + wm * 64 + (lane >> 4) * 4;
  const int cloc = wn * 64 + (lane & 15);  // local col within 128-tile

  const float* bias = (which == 0) ? bq : (which == 1) ? bk : bv;
#pragma unroll
  for (int fn = 0; fn < 4; ++fn) {
    const int colF = feat0 + cloc + fn * 16;  // feature index 0..1023
    const float bvv = bias[colF];
#pragma unroll
    for (int fm = 0; fm < 4; ++fm)
#pragma unroll
      for (int j = 0; j < 4; ++j) {
        float v = acc[fm][fn][j] + bvv;
        if (which < 2) {  // rope for Q,K (wave-uniform branch)
          const int s = (rbase + fm * 16 + j) & (kS - 1);
          const float cc = fcos[s * (kD / 2) + (colF >> 1)];
          const float ss = fsin[s * (kD / 2) + (colF >> 1)];
          const float p = __shfl_xor(v, 1);  // partner col (colF^1)
          v = (colF & 1) ? (p * ss + v * cc) : (v * cc - p * ss);
        }
        acc[fm][fn][j] = v;
      }
  }

  if (which == 0) {  // Q: flat f16 store [m][feat]
#pragma unroll
    for (int fm = 0; fm < 4; ++fm)
#pragma unroll
      for (int fn = 0; fn < 4; ++fn)
#pragma unroll
        for (int j = 0; j < 4; ++j)
          qh[(size_t)(rbase + fm * 16 + j) * kD + feat0 + cloc + fn * 16] =
              (f16)acc[fm][fn][j];
  } else {  // K/V: transposed store [b][feat][s] via LDS re-stage
    f16* tbuf = (f16*)smem_raw;  // [128][136]
#pragma unroll
    for (int fm = 0; fm < 4; ++fm)
#pragma unroll
      for (int fn = 0; fn < 4; ++fn) {
        f16x4 pk = {(f16)acc[fm][fn][0], (f16)acc[fm][fn][1],
                    (f16)acc[fm][fn][2], (f16)acc[fm][fn][3]};
        const int rT = wn * 64 + fn * 16 + (lane & 15);      // feat-dim
        const int cT = wm * 64 + fm * 16 + (lane >> 4) * 4;  // s-dim
        *reinterpret_cast<f16x4*>(tbuf + rT * 136 + cT) = pk;
      }
    __syncthreads();
    const int bidx = m0 >> 12;
    const int sbase = m0 & (kS - 1);
    f16* Ct = ((which == 1) ? Kt : Vt) + (size_t)bidx * kD * kS + sbase;
#pragma unroll
    for (int it = 0; it < 8; ++it) {
      const int idx = it * 256 + tid;
      const int rn = idx >> 4, ch = idx & 15;
      f16x8 vv = *reinterpret_cast<const f16x8*>(tbuf + rn * 136 + ch * 8);
      *reinterpret_cast<f16x8*>(Ct + (size_t)(feat0 + rn) * kS + ch * 8) = vv;
    }
  }
}

// ---- ktv: part[z][n][o] = sum_s Vt[n][s]*Kt[o][s], z=(b,split). grid 512 ----
__global__ __launch_bounds__(256) void ktv_kernel(const f16* __restrict__ Kt,
                                                  const f16* __restrict__ Vt,
                                                  float* __restrict__ part) {
  __shared__ __align__(16) unsigned char smem_raw[32768];
  f16* sA = (f16*)smem_raw;
  f16* sB = sA + TM * BK;

  const int bid = blockIdx.x;
  const int l = (bid & 7) * 64 + (bid >> 3);  // XCD c owns z==c entirely
  const int z = l >> 6;                       // (b, split)
  const int r = l & 63;
  const int ct = r >> 3;  // B (Kt) tile, resident per round
  const int rp = r & 7;   // A (Vt) panel, streamed
  const int m0 = rp * 128, n0 = ct * 128;
  const size_t off = (size_t)(z >> 1) * kD * kS + (size_t)(z & 1) * (kS / 2);

  f32x4 acc[4][4];
  gemm_core<kS, kS, (kS / 2) / BK>(Vt + off + (size_t)m0 * kS,
                                   Kt + off + (size_t)n0 * kS, sA, sB, acc);

  const int tid = threadIdx.x;
  const int w = tid >> 6, lane = tid & 63;
  const int wm = w >> 1, wn = w & 1;
  const int rbase = m0 + wm * 64 + (lane >> 4) * 4;
  const int cbase = n0 + wn * 64 + (lane & 15);
  float* C = part + ((size_t)z << 20);
#pragma unroll
  for (int fm = 0; fm < 4; ++fm)
#pragma unroll
    for (int fn = 0; fn < 4; ++fn)
#pragma unroll
      for (int j = 0; j < 4; ++j)
        C[(size_t)(rbase + fm * 16 + j) * kD + cbase + fn * 16] = acc[fm][fn][j];
}

// ---- qm: out[m][n] = 0.25 * sum_o qh[m][o] * Mt[b][n][o]. grid 1024 ----
__global__ __launch_bounds__(256) void qm_kernel(const f16* __restrict__ qh,
                                                 const f16* __restrict__ Mt,
                                                 float* __restrict__ Out) {
  __shared__ __align__(16) unsigned char smem_raw[32768];
  f16* sA = (f16*)smem_raw;
  f16* sB = sA + TM * BK;

  const int bid = blockIdx.x;
  const int l = (bid & 7) * 128 + (bid >> 3);
  const int rpc = l >> 7;  // XCD chunk: 16 row panels (4MB A-set)
  const int r = l & 127;
  const int ct = r >> 4;               // 0..7
  const int rp = rpc * 16 + (r & 15);  // 0..127
  const int m0 = rp * 128, n0 = ct * 128;
  const int b = m0 >> 12;  // chunk spans single batch (16 panels = 2048 rows)

  f32x4 acc[4][4];
  gemm_core<kD, kD, kD / BK>(qh + (size_t)m0 * kD,
                             Mt + (size_t)b * kD * kD + (size_t)n0 * kD, sA, sB,
                             acc);

  const int tid = threadIdx.x;
  const int w = tid >> 6, lane = tid & 63;
  const int wm = w >> 1, wn = w & 1;
  const int rbase = m0 + wm * 64 + (lane >> 4) * 4;
  const int cbase = n0 + wn * 64 + (lane & 15);
#pragma unroll
  for (int fm = 0; fm < 4; ++fm)
#pragma unroll
    for (int fn = 0; fn < 4; ++fn)
#pragma unroll
      for (int j = 0; j < 4; ++j)
        Out[(size_t)(rbase + fm * 16 + j) * kD + cbase + fn * 16] =
            0.25f * acc[fm][fn][j];
}

extern "C" void kernel_launch(void* const* d_in, const int* in_sizes, int n_in,
                              void* d_out, int out_size, void* d_ws,
                              size_t ws_size, hipStream_t stream) {
  const float* x = (const float*)d_in[0];
  const float* fcos = (const float*)d_in[1];
  const float* fsin = (const float*)d_in[2];
  const float* wq = (const float*)d_in[3];
  const float* bq = (const float*)d_in[4];
  const float* wk = (const float*)d_in[5];
  const float* bk = (const float*)d_in[6];
  const float* wv = (const float*)d_in[7];
  const float* bv = (const float*)d_in[8];

  char* ws = (char*)d_ws;
  f16* xh = (f16*)ws;                            // 32 MiB (dead after proj)
  float* part = (float*)ws;                      // 32 MiB (aliases xh)
  f16* Wall = (f16*)(ws + ((size_t)32 << 20));   // 6 MiB [Wq;Wk;Wv]
  f16* Mt = (f16*)(ws + ((size_t)38 << 20));     // 8 MiB
  f16* qh = (f16*)(ws + ((size_t)46 << 20));     // 32 MiB (live until qm)
  f16* Kt = (f16*)d_out;                         // d_out lo 32 MiB (scratch)
  f16* Vt = (f16*)d_out + ((size_t)16 << 20);    // d_out hi 32 MiB (scratch)

  dim3 blk(256);
  cast_f2h<<<2048, blk, 0, stream>>>(x, xh, kBS * kD);
  cast_f2h<<<512, blk, 0, stream>>>(wq, Wall, kD * kD);
  cast_f2h<<<512, blk, 0, stream>>>(wk, Wall + kD * kD, kD * kD);
  cast_f2h<<<512, blk, 0, stream>>>(wv, Wall + 2 * kD * kD, kD * kD);

  fused_proj<<<3072, blk, 0, stream>>>(xh, Wall, bq, bk, bv, fcos, fsin, qh, Kt,
                                       Vt);
  ktv_kernel<<<512, blk, 0, stream>>>(Kt, Vt, part);
  reduce_mt<<<2048, blk, 0, stream>>>(part, Mt);
  qm_kernel<<<1024, blk, 0, stream>>>(qh, Mt, (float*)d_out);
}

// Round 9
// 404.738 us; speedup vs baseline: 1.1054x; 1.1054x over previous
//
#include <hip/hip_runtime.h>

// MHA-no-softmax, re-associated:  out = rope(XWq+bq) · [ (rope(XWk+bk))^T (XWv+bv) ] / 4
// Round 7: revert to SEPARATE projections (round-5 validated core + epilogues);
// add per-XCD panel-chunked assignment sized to fit the 4MB L2:
//   proj/qm: XCD c owns row-panels [16c,16c+16), col-inner (8 same-panel blocks
//            adjacent) -> B (2MB) L2-hot, A streamed once per XCD.
//   ktv:     XCD c owns z=(b,split)=c, col-inner.
// Round-6 failure: fused Wall (6MB) + 4MB A-chunk thrashed L2 (FETCH variance
// across replays = thrash signature). B must be <=2MB to stay resident.
// GEMM core unchanged: 128x128, BK=64, 4 waves, mfma_f32_16x16x32_f16,
// global_load_lds w=16, XOR-swizzled LDS reads (rule #21).

typedef _Float16 f16;
typedef _Float16 f16x8 __attribute__((ext_vector_type(8)));
typedef _Float16 f16x4 __attribute__((ext_vector_type(4)));
typedef float f32x4 __attribute__((ext_vector_type(4)));

namespace {
constexpr int kB = 4, kS = 4096, kD = 1024;
constexpr int kBS = kB * kS;  // 16384
constexpr int TM = 128, TN = 128, BK = 64;
enum { EPI_QPROJ, EPI_KPROJ, EPI_VPROJ, EPI_KTV, EPI_QM };
}  // namespace

__device__ __forceinline__ void gld_lds16(const f16* g, f16* l) {
  __builtin_amdgcn_global_load_lds(
      (const __attribute__((address_space(1))) unsigned int*)g,
      (__attribute__((address_space(3))) unsigned int*)l, 16, 0, 0);
}

__global__ void cast_f2h(const float* __restrict__ src, f16* __restrict__ dst,
                         int n) {
  const int stride = gridDim.x * blockDim.x * 8;
  for (int i = (blockIdx.x * blockDim.x + threadIdx.x) * 8; i < n; i += stride) {
    float4 a = *reinterpret_cast<const float4*>(src + i);
    float4 b = *reinterpret_cast<const float4*>(src + i + 4);
    f16x8 o = {(f16)a.x, (f16)a.y, (f16)a.z, (f16)a.w,
               (f16)b.x, (f16)b.y, (f16)b.z, (f16)b.w};
    *reinterpret_cast<f16x8*>(dst + i) = o;
  }
}

// partials p[(b*2+split)][1M] fp32 -> Mt[b][1M] f16
__global__ void reduce_mt(const float* __restrict__ p, f16* __restrict__ mt) {
  const int i = (blockIdx.x * blockDim.x + threadIdx.x) * 8;  // < 4M
  const int b = i >> 20;
  const int w = i & ((1 << 20) - 1);
  const float* p0 = p + ((size_t)(2 * b) << 20) + w;
  const float* p1 = p0 + (1 << 20);
  float4 a0 = *reinterpret_cast<const float4*>(p0);
  float4 a1 = *reinterpret_cast<const float4*>(p0 + 4);
  float4 c0 = *reinterpret_cast<const float4*>(p1);
  float4 c1 = *reinterpret_cast<const float4*>(p1 + 4);
  f16x8 o = {(f16)(a0.x + c0.x), (f16)(a0.y + c0.y), (f16)(a0.z + c0.z),
             (f16)(a0.w + c0.w), (f16)(a1.x + c1.x), (f16)(a1.y + c1.y),
             (f16)(a1.z + c1.z), (f16)(a1.w + c1.w)};
  *reinterpret_cast<f16x8*>(mt + i) = o;
}

template <int EPI, int LDA, int LDB, int KSTEPS>
__global__ __launch_bounds__(256) void gemm_kernel(
    const f16* __restrict__ A, const f16* __restrict__ B,
    const float* __restrict__ bias, const float* __restrict__ fcos,
    const float* __restrict__ fsin, void* __restrict__ Cout) {
  __shared__ __align__(16) unsigned char smem_raw[34816];
  f16* sA = (f16*)smem_raw;
  f16* sB = sA + TM * BK;

  const int tid = threadIdx.x;
  const int w = tid >> 6, lane = tid & 63;
  const int wm = w >> 1, wn = w & 1;

  // --- per-XCD panel-chunked decode (bid%8 == XCD round-robin premise) ---
  int m0, n0, zidx = 0;
  const int bid = blockIdx.x;
  if constexpr (EPI == EPI_KTV) {
    const int l = (bid & 7) * 64 + (bid >> 3);  // XCD c owns z==c
    zidx = l >> 6;
    const int i = l & 63;
    m0 = (i >> 3) * TM;  // Vt panel (A, streamed once)
    n0 = (i & 7) * TN;   // Kt tile  (B-set 4MB, col-inner)
  } else {
    const int l = (bid & 7) * 128 + (bid >> 3);  // XCD c: panels [16c,16c+16)
    const int c = l >> 7;
    const int i = l & 127;
    m0 = (c * 16 + (i >> 3)) * TM;  // A panel: 8 readers co-located, tight
    n0 = (i & 7) * TN;              // B tile: 2MB, stays L2-hot
  }

  size_t aoff = (size_t)m0 * LDA;
  size_t boff = (size_t)n0 * LDB;
  if constexpr (EPI == EPI_KTV) {
    const int b = zidx >> 1, sp = zidx & 1;
    const size_t bo = (size_t)b * kD * kS + (size_t)sp * (kS / 2);
    aoff += bo;
    boff += bo;
  }
  if constexpr (EPI == EPI_QM) boff += (size_t)(m0 >> 12) * kD * kD;
  const f16* Ab = A + aoff;
  const f16* Bb = B + boff;

  const int srow = lane >> 3;         // row within 8-row chunk
  const int scolb = (lane & 7) * 16;  // col bytes within 128B row

  f32x4 acc[4][4];
#pragma unroll
  for (int i = 0; i < 4; ++i)
#pragma unroll
    for (int j = 0; j < 4; ++j) acc[i][j] = (f32x4){0.f, 0.f, 0.f, 0.f};

  for (int ks = 0; ks < KSTEPS; ++ks) {
    const int k0 = ks * BK;
    // linear LDS dest, inverse-swizzled global source (involution, rule #21)
#pragma unroll
    for (int i = 0; i < 4; ++i) {
      const int row = w * 32 + i * 8 + srow;
      const int fe = (scolb ^ ((row & 7) << 4)) >> 1;
      gld_lds16(Ab + (size_t)row * LDA + k0 + fe, sA + w * 2048 + i * 512);
      gld_lds16(Bb + (size_t)row * LDB + k0 + fe, sB + w * 2048 + i * 512);
    }
    __syncthreads();
#pragma unroll
    for (int kc = 0; kc < 2; ++kc) {
      const int clog = kc * 64 + (lane >> 4) * 16;  // logical col bytes
      f16x8 af[4], bf[4];
#pragma unroll
      for (int f = 0; f < 4; ++f) {
        const int ra = wm * 64 + f * 16 + (lane & 15);
        af[f] = *reinterpret_cast<const f16x8*>(
            sA + ra * BK + ((clog ^ ((ra & 7) << 4)) >> 1));
        const int rb = wn * 64 + f * 16 + (lane & 15);
        bf[f] = *reinterpret_cast<const f16x8*>(
            sB + rb * BK + ((clog ^ ((rb & 7) << 4)) >> 1));
      }
#pragma unroll
      for (int i = 0; i < 4; ++i)
#pragma unroll
        for (int j = 0; j < 4; ++j)
          acc[i][j] = __builtin_amdgcn_mfma_f32_16x16x32_f16(af[i], bf[j],
                                                             acc[i][j], 0, 0, 0);
    }
    __syncthreads();
  }

  // C/D layout: row = (lane>>4)*4 + reg, col = lane&15  (per fragment)
  const int rbase = m0 + wm * 64 + (lane >> 4) * 4;
  const int cbase = n0 + wn * 64 + (lane & 15);

  if constexpr (EPI == EPI_KTV) {
    float* C = (float*)Cout + ((size_t)zidx << 20);
#pragma unroll
    for (int fm = 0; fm < 4; ++fm)
#pragma unroll
      for (int fn = 0; fn < 4; ++fn)
#pragma unroll
        for (int j = 0; j < 4; ++j)
          C[(size_t)(rbase + fm * 16 + j) * kD + cbase + fn * 16] =
              acc[fm][fn][j];
  } else if constexpr (EPI == EPI_QM) {
    float* C = (float*)Cout;
#pragma unroll
    for (int fm = 0; fm < 4; ++fm)
#pragma unroll
      for (int fn = 0; fn < 4; ++fn)
#pragma unroll
        for (int j = 0; j < 4; ++j)
          C[(size_t)(rbase + fm * 16 + j) * kD + cbase + fn * 16] =
              0.25f * acc[fm][fn][j];
  } else {
    // projections: bias (+rope for Q/K) in fp32
#pragma unroll
    for (int fn = 0; fn < 4; ++fn) {
      const int col = cbase + fn * 16;
      const float bv = bias[col];
#pragma unroll
      for (int fm = 0; fm < 4; ++fm)
#pragma unroll
        for (int j = 0; j < 4; ++j) {
          float v = acc[fm][fn][j] + bv;
          if constexpr (EPI == EPI_QPROJ || EPI == EPI_KPROJ) {
            const int s = (rbase + fm * 16 + j) & (kS - 1);
            const int pair = col >> 1;
            const float cc = fcos[s * (kD / 2) + pair];
            const float ss = fsin[s * (kD / 2) + pair];
            const float p = __shfl_xor(v, 1);  // partner col (col^1)
            v = (col & 1) ? (p * ss + v * cc) : (v * cc - p * ss);
          }
          acc[fm][fn][j] = v;
        }
    }
    if constexpr (EPI == EPI_QPROJ) {
      f16* C = (f16*)Cout;
#pragma unroll
      for (int fm = 0; fm < 4; ++fm)
#pragma unroll
        for (int fn = 0; fn < 4; ++fn)
#pragma unroll
          for (int j = 0; j < 4; ++j)
            C[(size_t)(rbase + fm * 16 + j) * kD + cbase + fn * 16] =
                (f16)acc[fm][fn][j];
    } else {
      // K/V: transposed store [b][feat][s] via LDS re-stage (coalesced rows)
      f16* tbuf = (f16*)smem_raw;  // [128][136]
#pragma unroll
      for (int fm = 0; fm < 4; ++fm)
#pragma unroll
        for (int fn = 0; fn < 4; ++fn) {
          f16x4 pk = {(f16)acc[fm][fn][0], (f16)acc[fm][fn][1],
                      (f16)acc[fm][fn][2], (f16)acc[fm][fn][3]};
          const int rT = wn * 64 + fn * 16 + (lane & 15);      // feat-dim
          const int cT = wm * 64 + fm * 16 + (lane >> 4) * 4;  // s-dim
          *reinterpret_cast<f16x4*>(tbuf + rT * 136 + cT) = pk;
        }
      __syncthreads();
      const int bidx = m0 >> 12;
      const int sbase = m0 & (kS - 1);
      f16* Ct = (f16*)Cout + (size_t)bidx * kD * kS + sbase;
#pragma unroll
      for (int it = 0; it < 8; ++it) {
        const int idx = it * 256 + tid;
        const int rn = idx >> 4, ch = idx & 15;
        f16x8 vv = *reinterpret_cast<const f16x8*>(tbuf + rn * 136 + ch * 8);
        *reinterpret_cast<f16x8*>(Ct + (size_t)(n0 + rn) * kS + ch * 8) = vv;
      }
    }
  }
}

extern "C" void kernel_launch(void* const* d_in, const int* in_sizes, int n_in,
                              void* d_out, int out_size, void* d_ws,
                              size_t ws_size, hipStream_t stream) {
  const float* x = (const float*)d_in[0];
  const float* fcos = (const float*)d_in[1];
  const float* fsin = (const float*)d_in[2];
  const float* wq = (const float*)d_in[3];
  const float* bq = (const float*)d_in[4];
  const float* wk = (const float*)d_in[5];
  const float* bk = (const float*)d_in[6];
  const float* wv = (const float*)d_in[7];
  const float* bv = (const float*)d_in[8];

  char* ws = (char*)d_ws;
  f16* xh = (f16*)ws;                              // 32 MiB
  f16* wqh = (f16*)(ws + ((size_t)32 << 20));      // 2 MiB
  f16* wkh = (f16*)(ws + ((size_t)34 << 20));      // 2 MiB
  f16* wvh = (f16*)(ws + ((size_t)36 << 20));      // 2 MiB
  f16* Mt = (f16*)(ws + ((size_t)38 << 20));       // 8 MiB
  float* part = (float*)(ws + ((size_t)46 << 20)); // 32 MiB (dead after reduce)
  f16* qh = (f16*)(ws + ((size_t)46 << 20));       // 32 MiB (aliases part)
  f16* Kt = (f16*)d_out;                           // d_out lo 32 MiB (scratch)
  f16* Vt = (f16*)d_out + ((size_t)16 << 20);      // d_out hi 32 MiB (scratch)

  dim3 blk(256);
  cast_f2h<<<2048, blk, 0, stream>>>(x, xh, kBS * kD);
  cast_f2h<<<512, blk, 0, stream>>>(wq, wqh, kD * kD);
  cast_f2h<<<512, blk, 0, stream>>>(wk, wkh, kD * kD);
  cast_f2h<<<512, blk, 0, stream>>>(wv, wvh, kD * kD);

  gemm_kernel<EPI_KPROJ, kD, kD, kD / BK>
      <<<1024, blk, 0, stream>>>(xh, wkh, bk, fcos, fsin, Kt);
  gemm_kernel<EPI_VPROJ, kD, kD, kD / BK>
      <<<1024, blk, 0, stream>>>(xh, wvh, bv, nullptr, nullptr, Vt);
  gemm_kernel<EPI_KTV, kS, kS, (kS / 2) / BK>
      <<<512, blk, 0, stream>>>(Vt, Kt, nullptr, nullptr, nullptr, part);
  reduce_mt<<<2048, blk, 0, stream>>>(part, Mt);
  gemm_kernel<EPI_QPROJ, kD, kD, kD / BK>
      <<<1024, blk, 0, stream>>>(xh, wqh, bq, fcos, fsin, qh);
  gemm_kernel<EPI_QM, kD, kD, kD / BK>
      <<<1024, blk, 0, stream>>>(qh, Mt, nullptr, nullptr, nullptr,
                                 (float*)d_out);
}

// Round 10
// 379.000 us; speedup vs baseline: 1.1804x; 1.0679x over previous
//
#include <hip/hip_runtime.h>

// MHA-no-softmax, re-associated:  out = rope(XWq+bq) · [ (rope(XWk+bk))^T (XWv+bv) ] / 4
// Round 10: projections + qm move to 256x256/BK=64/512-thr/8-wave DOUBLE-BUFFERED
// 2-phase GEMM (T3-minimum): STAGE(next) issued BEFORE COMPUTE(cur), ONE barrier
// per K-tile -> staging HBM/L2 latency hides under 64 MFMA/wave. Round-9 showed
// latency-bound (MfmaUtil 17.8, VALU 26, occ 20, HBM 0.9 TB/s): the 2-barrier
// no-overlap structure was the limiter, not traffic (FETCH model confirmed).
// XCD-chunked decode kept (FETCH 149->67MB win). ktv/reduce/casts unchanged.
// Swizzle: same validated involution (rule #21) on stage-source and ds_read.

typedef _Float16 f16;
typedef _Float16 f16x8 __attribute__((ext_vector_type(8)));
typedef _Float16 f16x4 __attribute__((ext_vector_type(4)));
typedef float f32x4 __attribute__((ext_vector_type(4)));

namespace {
constexpr int kB = 4, kS = 4096, kD = 1024;
constexpr int kBS = kB * kS;  // 16384
constexpr int TM = 128, TN = 128, BK = 64;  // (TM/TN used by legacy ktv kernel)
enum { EPI_QPROJ, EPI_KPROJ, EPI_VPROJ, EPI_KTV, EPI_QM };
}  // namespace

__device__ __forceinline__ void gld_lds16(const f16* g, f16* l) {
  __builtin_amdgcn_global_load_lds(
      (const __attribute__((address_space(1))) unsigned int*)g,
      (__attribute__((address_space(3))) unsigned int*)l, 16, 0, 0);
}

__global__ void cast_f2h(const float* __restrict__ src, f16* __restrict__ dst,
                         int n) {
  const int stride = gridDim.x * blockDim.x * 8;
  for (int i = (blockIdx.x * blockDim.x + threadIdx.x) * 8; i < n; i += stride) {
    float4 a = *reinterpret_cast<const float4*>(src + i);
    float4 b = *reinterpret_cast<const float4*>(src + i + 4);
    f16x8 o = {(f16)a.x, (f16)a.y, (f16)a.z, (f16)a.w,
               (f16)b.x, (f16)b.y, (f16)b.z, (f16)b.w};
    *reinterpret_cast<f16x8*>(dst + i) = o;
  }
}

// partials p[(b*2+split)][1M] fp32 -> Mt[b][1M] f16
__global__ void reduce_mt(const float* __restrict__ p, f16* __restrict__ mt) {
  const int i = (blockIdx.x * blockDim.x + threadIdx.x) * 8;  // < 4M
  const int b = i >> 20;
  const int w = i & ((1 << 20) - 1);
  const float* p0 = p + ((size_t)(2 * b) << 20) + w;
  const float* p1 = p0 + (1 << 20);
  float4 a0 = *reinterpret_cast<const float4*>(p0);
  float4 a1 = *reinterpret_cast<const float4*>(p0 + 4);
  float4 c0 = *reinterpret_cast<const float4*>(p1);
  float4 c1 = *reinterpret_cast<const float4*>(p1 + 4);
  f16x8 o = {(f16)(a0.x + c0.x), (f16)(a0.y + c0.y), (f16)(a0.z + c0.z),
             (f16)(a0.w + c0.w), (f16)(a1.x + c1.x), (f16)(a1.y + c1.y),
             (f16)(a1.z + c1.z), (f16)(a1.w + c1.w)};
  *reinterpret_cast<f16x8*>(mt + i) = o;
}

// ============ 256x256 / BK=64 / 512-thread / 8-wave / 2-phase dbuf ============
template <int EPI, int LDA, int LDB, int KSTEPS>
__global__ __launch_bounds__(512, 2) void gemm256(
    const f16* __restrict__ A, const f16* __restrict__ B,
    const float* __restrict__ bias, const float* __restrict__ fcos,
    const float* __restrict__ fsin, void* __restrict__ Cout) {
  // sA[2][256][64] + sB[2][256][64] f16 = 128 KiB (dbuf); epilogue tbuf aliases
  __shared__ __align__(16) unsigned char smem_raw[131072];
  f16* sAq = (f16*)smem_raw;   // 2 x 16384 f16
  f16* sBq = sAq + 32768;      // 2 x 16384 f16

  const int tid = threadIdx.x;
  const int w = tid >> 6, lane = tid & 63;
  const int wm = w >> 2, wn = w & 3;  // 2M x 4N wave grid; wave tile 128x64

  // XCD c (=bid%8) owns mtiles [8c,8c+8), ntiles inner (L2: B-tile + A-chunk)
  const int bid = blockIdx.x;
  const int l = (bid & 7) * 32 + (bid >> 3);  // grid 256 -> bijective
  const int mt = (l >> 5) * 8 + ((l & 31) >> 2);
  const int nt = l & 3;
  const int m0 = mt * 256, n0 = nt * 256;

  const f16* Ab = A + (size_t)m0 * LDA;
  const f16* Bb = B + (size_t)n0 * LDB +
                  (EPI == EPI_QM ? (size_t)(m0 >> 12) * kD * kD : (size_t)0);

  const int srow = lane >> 3;         // staging: row within 8-row chunk
  const int scolb = (lane & 7) * 16;  // col bytes within 128B row

  f32x4 acc[8][4];
#pragma unroll
  for (int i = 0; i < 8; ++i)
#pragma unroll
    for (int j = 0; j < 4; ++j) acc[i][j] = (f32x4){0.f, 0.f, 0.f, 0.f};

  // stage one K-tile (A:256x64 + B:256x64) into buffer `buf`
  auto STAGE = [&](int buf, int ks) {
    const int k0 = ks * BK;
#pragma unroll
    for (int i = 0; i < 4; ++i) {
      const int row = w * 32 + i * 8 + srow;
      const int fe = (scolb ^ ((row & 7) << 4)) >> 1;  // inverse-swizzled src
      gld_lds16(Ab + (size_t)row * LDA + k0 + fe,
                sAq + buf * 16384 + w * 2048 + i * 512);
      gld_lds16(Bb + (size_t)row * LDB + k0 + fe,
                sBq + buf * 16384 + w * 2048 + i * 512);
    }
  };

  auto COMPUTE = [&](int buf) {
    const f16* bA = sAq + buf * 16384;
    const f16* bB = sBq + buf * 16384;
#pragma unroll
    for (int kc = 0; kc < 2; ++kc) {
      const int clog = kc * 64 + (lane >> 4) * 16;  // logical col bytes
      f16x8 af[8], bf[4];
#pragma unroll
      for (int f = 0; f < 8; ++f) {
        const int ra = wm * 128 + f * 16 + (lane & 15);
        af[f] = *reinterpret_cast<const f16x8*>(
            bA + ra * 64 + ((clog ^ ((ra & 7) << 4)) >> 1));
      }
#pragma unroll
      for (int f = 0; f < 4; ++f) {
        const int rb = wn * 64 + f * 16 + (lane & 15);
        bf[f] = *reinterpret_cast<const f16x8*>(
            bB + rb * 64 + ((clog ^ ((rb & 7) << 4)) >> 1));
      }
#pragma unroll
      for (int i = 0; i < 8; ++i)
#pragma unroll
        for (int j = 0; j < 4; ++j)
          acc[i][j] = __builtin_amdgcn_mfma_f32_16x16x32_f16(af[i], bf[j],
                                                             acc[i][j], 0, 0, 0);
    }
  };

  // 2-phase: prologue stage; per iter {issue next-tile loads; compute; ONE sync}
  STAGE(0, 0);
  __syncthreads();
  int buf = 0;
  for (int t = 0; t < KSTEPS - 1; ++t) {
    STAGE(buf ^ 1, t + 1);  // loads fly under COMPUTE's ds_read+MFMA
    COMPUTE(buf);
    __syncthreads();  // drains vmcnt+lgkmcnt (compiler) -> next tile ready
    buf ^= 1;
  }
  COMPUTE(buf);

  // C/D: row = rb0 + fm*16 + j, col = n0 + cloc + fn*16
  const int rb0 = m0 + wm * 128 + (lane >> 4) * 4;
  const int cloc = wn * 64 + (lane & 15);

  if constexpr (EPI == EPI_QM) {
    float* C = (float*)Cout;
#pragma unroll
    for (int fm = 0; fm < 8; ++fm)
#pragma unroll
      for (int fn = 0; fn < 4; ++fn)
#pragma unroll
        for (int j = 0; j < 4; ++j)
          C[(size_t)(rb0 + fm * 16 + j) * kD + n0 + cloc + fn * 16] =
              0.25f * acc[fm][fn][j];
  } else {
    // bias (+rope for Q/K) in fp32
#pragma unroll
    for (int fn = 0; fn < 4; ++fn) {
      const int colF = n0 + cloc + fn * 16;
      const float bvv = bias[colF];
#pragma unroll
      for (int fm = 0; fm < 8; ++fm)
#pragma unroll
        for (int j = 0; j < 4; ++j) {
          float v = acc[fm][fn][j] + bvv;
          if constexpr (EPI == EPI_QPROJ || EPI == EPI_KPROJ) {
            const int s = (rb0 + fm * 16 + j) & (kS - 1);
            const float cc = fcos[s * (kD / 2) + (colF >> 1)];
            const float ss = fsin[s * (kD / 2) + (colF >> 1)];
            const float p = __shfl_xor(v, 1);  // partner col (colF^1)
            v = (colF & 1) ? (p * ss + v * cc) : (v * cc - p * ss);
          }
          acc[fm][fn][j] = v;
        }
    }
    if constexpr (EPI == EPI_QPROJ) {
      f16* C = (f16*)Cout;
#pragma unroll
      for (int fm = 0; fm < 8; ++fm)
#pragma unroll
        for (int fn = 0; fn < 4; ++fn)
#pragma unroll
          for (int j = 0; j < 4; ++j)
            C[(size_t)(rb0 + fm * 16 + j) * kD + n0 + cloc + fn * 16] =
                (f16)acc[fm][fn][j];
    } else {
      // K/V: transposed store [b][feat][s], two 128-feat passes through LDS
      __syncthreads();  // sA/sB dead -> reuse as tbuf [128][264] f16 (67.5KB)
      f16* tbuf = (f16*)smem_raw;
      const int bidx = m0 >> 12;
      const int sbase = m0 & (kS - 1);
      f16* Ct = (f16*)Cout + (size_t)bidx * kD * kS + sbase;
#pragma unroll
      for (int h = 0; h < 2; ++h) {
        if ((wn >> 1) == h) {
#pragma unroll
          for (int fm = 0; fm < 8; ++fm)
#pragma unroll
            for (int fn = 0; fn < 4; ++fn) {
              f16x4 pk = {(f16)acc[fm][fn][0], (f16)acc[fm][fn][1],
                          (f16)acc[fm][fn][2], (f16)acc[fm][fn][3]};
              const int rT = (wn & 1) * 64 + fn * 16 + (lane & 15);  // feat&127
              const int cT = wm * 128 + fm * 16 + (lane >> 4) * 4;   // s-dim
              *reinterpret_cast<f16x4*>(tbuf + rT * 264 + cT) = pk;
            }
        }
        __syncthreads();
#pragma unroll
        for (int it = 0; it < 8; ++it) {
          const int idx = it * 512 + tid;
          const int rn = idx >> 5, ch = idx & 31;
          f16x8 vv = *reinterpret_cast<const f16x8*>(tbuf + rn * 264 + ch * 8);
          *reinterpret_cast<f16x8*>(
              Ct + (size_t)(n0 + h * 128 + rn) * kS + ch * 8) = vv;
        }
        __syncthreads();
      }
    }
  }
}

// ============ legacy 128x128 kernel: KTV only (validated rounds 5-9) ==========
template <int EPI, int LDA, int LDB, int KSTEPS>
__global__ __launch_bounds__(256) void gemm_kernel(
    const f16* __restrict__ A, const f16* __restrict__ B,
    const float* __restrict__ bias, const float* __restrict__ fcos,
    const float* __restrict__ fsin, void* __restrict__ Cout) {
  __shared__ __align__(16) unsigned char smem_raw[34816];
  f16* sA = (f16*)smem_raw;
  f16* sB = sA + TM * BK;

  const int tid = threadIdx.x;
  const int w = tid >> 6, lane = tid & 63;
  const int wm = w >> 1, wn = w & 1;

  int m0, n0, zidx = 0;
  const int bid = blockIdx.x;
  {
    const int l = (bid & 7) * 64 + (bid >> 3);  // XCD c owns z==c
    zidx = l >> 6;
    const int i = l & 63;
    m0 = (i >> 3) * TM;  // Vt panel (A)
    n0 = (i & 7) * TN;   // Kt tile  (B)
  }

  size_t aoff = (size_t)m0 * LDA;
  size_t boff = (size_t)n0 * LDB;
  {
    const int b = zidx >> 1, sp = zidx & 1;
    const size_t bo = (size_t)b * kD * kS + (size_t)sp * (kS / 2);
    aoff += bo;
    boff += bo;
  }
  const f16* Ab = A + aoff;
  const f16* Bb = B + boff;

  const int srow = lane >> 3;
  const int scolb = (lane & 7) * 16;

  f32x4 acc[4][4];
#pragma unroll
  for (int i = 0; i < 4; ++i)
#pragma unroll
    for (int j = 0; j < 4; ++j) acc[i][j] = (f32x4){0.f, 0.f, 0.f, 0.f};

  for (int ks = 0; ks < KSTEPS; ++ks) {
    const int k0 = ks * BK;
#pragma unroll
    for (int i = 0; i < 4; ++i) {
      const int row = w * 32 + i * 8 + srow;
      const int fe = (scolb ^ ((row & 7) << 4)) >> 1;
      gld_lds16(Ab + (size_t)row * LDA + k0 + fe, sA + w * 2048 + i * 512);
      gld_lds16(Bb + (size_t)row * LDB + k0 + fe, sB + w * 2048 + i * 512);
    }
    __syncthreads();
#pragma unroll
    for (int kc = 0; kc < 2; ++kc) {
      const int clog = kc * 64 + (lane >> 4) * 16;
      f16x8 af[4], bf[4];
#pragma unroll
      for (int f = 0; f < 4; ++f) {
        const int ra = wm * 64 + f * 16 + (lane & 15);
        af[f] = *reinterpret_cast<const f16x8*>(
            sA + ra * BK + ((clog ^ ((ra & 7) << 4)) >> 1));
        const int rb = wn * 64 + f * 16 + (lane & 15);
        bf[f] = *reinterpret_cast<const f16x8*>(
            sB + rb * BK + ((clog ^ ((rb & 7) << 4)) >> 1));
      }
#pragma unroll
      for (int i = 0; i < 4; ++i)
#pragma unroll
        for (int j = 0; j < 4; ++j)
          acc[i][j] = __builtin_amdgcn_mfma_f32_16x16x32_f16(af[i], bf[j],
                                                             acc[i][j], 0, 0, 0);
    }
    __syncthreads();
  }

  const int rbase = m0 + wm * 64 + (lane >> 4) * 4;
  const int cbase = n0 + wn * 64 + (lane & 15);
  float* C = (float*)Cout + ((size_t)zidx << 20);
#pragma unroll
  for (int fm = 0; fm < 4; ++fm)
#pragma unroll
    for (int fn = 0; fn < 4; ++fn)
#pragma unroll
      for (int j = 0; j < 4; ++j)
        C[(size_t)(rbase + fm * 16 + j) * kD + cbase + fn * 16] = acc[fm][fn][j];
}

extern "C" void kernel_launch(void* const* d_in, const int* in_sizes, int n_in,
                              void* d_out, int out_size, void* d_ws,
                              size_t ws_size, hipStream_t stream) {
  const float* x = (const float*)d_in[0];
  const float* fcos = (const float*)d_in[1];
  const float* fsin = (const float*)d_in[2];
  const float* wq = (const float*)d_in[3];
  const float* bq = (const float*)d_in[4];
  const float* wk = (const float*)d_in[5];
  const float* bk = (const float*)d_in[6];
  const float* wv = (const float*)d_in[7];
  const float* bv = (const float*)d_in[8];

  char* ws = (char*)d_ws;
  f16* xh = (f16*)ws;                              // 32 MiB
  f16* wqh = (f16*)(ws + ((size_t)32 << 20));      // 2 MiB
  f16* wkh = (f16*)(ws + ((size_t)34 << 20));      // 2 MiB
  f16* wvh = (f16*)(ws + ((size_t)36 << 20));      // 2 MiB
  f16* Mt = (f16*)(ws + ((size_t)38 << 20));       // 8 MiB
  float* part = (float*)(ws + ((size_t)46 << 20)); // 32 MiB (dead after reduce)
  f16* qh = (f16*)(ws + ((size_t)46 << 20));       // 32 MiB (aliases part)
  f16* Kt = (f16*)d_out;                           // d_out lo 32 MiB (scratch)
  f16* Vt = (f16*)d_out + ((size_t)16 << 20);      // d_out hi 32 MiB (scratch)

  dim3 blk(256), blk512(512);
  cast_f2h<<<2048, blk, 0, stream>>>(x, xh, kBS * kD);
  cast_f2h<<<512, blk, 0, stream>>>(wq, wqh, kD * kD);
  cast_f2h<<<512, blk, 0, stream>>>(wk, wkh, kD * kD);
  cast_f2h<<<512, blk, 0, stream>>>(wv, wvh, kD * kD);

  gemm256<EPI_KPROJ, kD, kD, kD / BK>
      <<<256, blk512, 0, stream>>>(xh, wkh, bk, fcos, fsin, Kt);
  gemm256<EPI_VPROJ, kD, kD, kD / BK>
      <<<256, blk512, 0, stream>>>(xh, wvh, bv, nullptr, nullptr, Vt);
  gemm_kernel<EPI_KTV, kS, kS, (kS / 2) / BK>
      <<<512, blk, 0, stream>>>(Vt, Kt, nullptr, nullptr, nullptr, part);
  reduce_mt<<<2048, blk, 0, stream>>>(part, Mt);
  gemm256<EPI_QPROJ, kD, kD, kD / BK>
      <<<256, blk512, 0, stream>>>(xh, wqh, bq, fcos, fsin, qh);
  gemm256<EPI_QM, kD, kD, kD / BK>
      <<<256, blk512, 0, stream>>>(qh, Mt, nullptr, nullptr, nullptr,
                                   (float*)d_out);
}